// Round 1
// baseline (48737.289 us; speedup 1.0000x reference)
//
#include <hip/hip_runtime.h>
#include <hip/hip_bf16.h>
#include <hip/hip_cooperative_groups.h>

namespace cg = cooperative_groups;

#define Bz  256
#define Tz  512
#define Hz  512
#define BHz (Bz*Hz)   // elements in one h buffer

typedef __bf16 bf16x8 __attribute__((ext_vector_type(8)));
typedef float  f32x4  __attribute__((ext_vector_type(4)));

__device__ __forceinline__ float sigf(float x)   { return 1.0f/(1.0f+__expf(-x)); }
__device__ __forceinline__ float tanhf_(float x) { return 2.0f/(1.0f+__expf(-2.0f*x)) - 1.0f; }

// ---- pack w_hh1 [512][2048] f32 -> bf16 MFMA B-fragment layout ----
// layout: [nt(128)][kb(16)][lane(64)][i(8)]; value = W[kb*32 + (lane>>4)*8 + i][nt*16 + (lane&15)]
__global__ void pack_w1(const float* __restrict__ w, __bf16* __restrict__ out){
    int idx = blockIdx.x*256 + threadIdx.x;           // 1,048,576 total
    int i = idx & 7, lane = (idx>>3)&63, kb = (idx>>9)&15, nt = idx>>13;
    int k   = kb*32 + (lane>>4)*8 + i;
    int col = nt*16 + (lane&15);
    out[idx] = (__bf16)w[k*2048 + col];
}

// ---- pack [w_ih2; w_hh2] (K=1024) with layer-2 gate-interleaved column order ----
// layout: [nt2(64)][kb(32)][f(2)][lane(64)][i(8)]
// cc = f*16 + (lane&15); col = (cc>>3)*512 + nt2*8 + (cc&7); k = kb*32 + (lane>>4)*8 + i
__global__ void pack_w2(const float* __restrict__ wih, const float* __restrict__ whh,
                        __bf16* __restrict__ out){
    int idx = blockIdx.x*256 + threadIdx.x;           // 2,097,152 total
    int i = idx & 7, lane = (idx>>3)&63, f = (idx>>9)&1, kb = (idx>>10)&31, nt = idx>>15;
    int k  = kb*32 + (lane>>4)*8 + i;
    int cc = f*16 + (lane&15);
    int col = (cc>>3)*512 + nt*8 + (cc&7);
    float v = (k < 512) ? wih[k*2048 + col] : whh[(k-512)*2048 + col];
    out[idx] = (__bf16)v;
}

__global__ void pack_bias(const float* a, const float* b, const float* c, const float* d,
                          float* b1s, float* b2s){
    int i = blockIdx.x*256 + threadIdx.x;
    if (i < 2048){ b1s[i] = a[i]+b[i]; b2s[i] = c[i]+d[i]; }
}

// ---- persistent pipelined 2-layer LSTM ----
// blocks 0..127  : layer1 tile (64 rows x 16 hcols x 4 gates), step p
// blocks 128..383: layer2 tile (64 rows x  8 hcols x 4 gates), step p-1
// one grid.sync per phase; c1/c2 live in registers for all 512 steps.
__launch_bounds__(256, 2)
__global__ void lstm_persistent(const float* __restrict__ x,      // [B][T][2]
                                const float* __restrict__ wih1,   // [2][2048]
                                const float* __restrict__ b1s,    // [2048]
                                const float* __restrict__ b2s,    // [2048]
                                const __bf16* __restrict__ w1p,
                                const __bf16* __restrict__ w2p,
                                __bf16* __restrict__ h1b,         // 2 x [B][H]
                                __bf16* __restrict__ h2b)         // 2 x [B][H]
{
    cg::grid_group grid = cg::this_grid();
    const int w    = blockIdx.x;
    const int tid  = threadIdx.x;
    const int v    = tid >> 6;
    const int lane = tid & 63;
    const int lhi  = lane >> 4, llo = lane & 15;

    if (w < 128){
        // ---------------- layer 1 ----------------
        const int mt = w >> 5, ntw = w & 31;
        const int row_base = mt*64 + v*16;
        const int j = ntw*16 + llo;                 // hidden col for C/D lane mapping
        float wa[4], wb[4], bb[4];
        #pragma unroll
        for (int g = 0; g < 4; ++g){
            int col = g*512 + j;
            wa[g] = wih1[col]; wb[g] = wih1[2048 + col]; bb[g] = b1s[col];
        }
        const __bf16* bp[4];
        #pragma unroll
        for (int g = 0; g < 4; ++g) bp[g] = w1p + (size_t)(g*32 + ntw)*8192 + lane*8;
        const int aoff = (row_base + llo)*Hz + lhi*8;
        const float2* x2 = reinterpret_cast<const float2*>(x);
        float c1[4] = {0.f,0.f,0.f,0.f};

        for (int p = 0; p <= Tz; ++p){
            if (p < Tz){
                const __bf16* h1prev = h1b + ((p+1)&1)*BHz;
                __bf16*       h1next = h1b + (p&1)*BHz;
                f32x4 a0={0,0,0,0}, a1={0,0,0,0}, a2={0,0,0,0}, a3={0,0,0,0};
                #pragma unroll 2
                for (int kb = 0; kb < 16; ++kb){
                    bf16x8 af = *reinterpret_cast<const bf16x8*>(h1prev + aoff + kb*32);
                    bf16x8 b0 = *reinterpret_cast<const bf16x8*>(bp[0] + kb*512);
                    bf16x8 b1 = *reinterpret_cast<const bf16x8*>(bp[1] + kb*512);
                    bf16x8 b2 = *reinterpret_cast<const bf16x8*>(bp[2] + kb*512);
                    bf16x8 b3 = *reinterpret_cast<const bf16x8*>(bp[3] + kb*512);
                    a0 = __builtin_amdgcn_mfma_f32_16x16x32_bf16(af, b0, a0, 0,0,0);
                    a1 = __builtin_amdgcn_mfma_f32_16x16x32_bf16(af, b1, a1, 0,0,0);
                    a2 = __builtin_amdgcn_mfma_f32_16x16x32_bf16(af, b2, a2, 0,0,0);
                    a3 = __builtin_amdgcn_mfma_f32_16x16x32_bf16(af, b3, a3, 0,0,0);
                }
                #pragma unroll
                for (int q = 0; q < 4; ++q){
                    int row = row_base + lhi*4 + q;
                    float2 xv = x2[row*Tz + p];
                    float gi = a0[q] + xv.x*wa[0] + xv.y*wb[0] + bb[0];
                    float gf = a1[q] + xv.x*wa[1] + xv.y*wb[1] + bb[1];
                    float gg = a2[q] + xv.x*wa[2] + xv.y*wb[2] + bb[2];
                    float go = a3[q] + xv.x*wa[3] + xv.y*wb[3] + bb[3];
                    float cn = sigf(gf)*c1[q] + sigf(gi)*tanhf_(gg);
                    c1[q] = cn;
                    h1next[row*Hz + j] = (__bf16)(sigf(go)*tanhf_(cn));
                }
            }
            __builtin_amdgcn_fence(__ATOMIC_RELEASE, "agent");
            grid.sync();
            __builtin_amdgcn_fence(__ATOMIC_ACQUIRE, "agent");
        }
    } else {
        // ---------------- layer 2 ----------------
        const int u = w - 128;
        const int nt2 = u >> 2, mt = u & 3;
        const int row_base = mt*64 + v*16;
        const int j = nt2*8 + (lane & 7);
        const int bit3 = (lane >> 3) & 1;
        const float beta0 = b2s[bit3*512 + j];        // i (bit3=0) or f (bit3=1)
        const float beta1 = b2s[(2 + bit3)*512 + j];  // g or o
        const int aoff = (row_base + llo)*Hz + lhi*8;
        const __bf16* b2base = w2p + (size_t)nt2*32768 + lane*8;
        float c2[4] = {0.f,0.f,0.f,0.f};

        for (int p = 0; p <= Tz; ++p){
            if (p >= 1){
                const __bf16* h1cur  = h1b + ((p+1)&1)*BHz;   // h1[p-1]
                const __bf16* h2prev = h2b + (p&1)*BHz;       // h2[p-2]
                __bf16*       h2next = h2b + ((p+1)&1)*BHz;   // h2[p-1]
                f32x4 a0={0,0,0,0}, a1={0,0,0,0};
                #pragma unroll 2
                for (int kb = 0; kb < 16; ++kb){
                    bf16x8 af = *reinterpret_cast<const bf16x8*>(h1cur + aoff + kb*32);
                    bf16x8 b0 = *reinterpret_cast<const bf16x8*>(b2base + kb*1024);
                    bf16x8 b1 = *reinterpret_cast<const bf16x8*>(b2base + kb*1024 + 512);
                    a0 = __builtin_amdgcn_mfma_f32_16x16x32_bf16(af, b0, a0, 0,0,0);
                    a1 = __builtin_amdgcn_mfma_f32_16x16x32_bf16(af, b1, a1, 0,0,0);
                }
                #pragma unroll 2
                for (int kb = 16; kb < 32; ++kb){
                    bf16x8 af = *reinterpret_cast<const bf16x8*>(h2prev + aoff + (kb-16)*32);
                    bf16x8 b0 = *reinterpret_cast<const bf16x8*>(b2base + kb*1024);
                    bf16x8 b1 = *reinterpret_cast<const bf16x8*>(b2base + kb*1024 + 512);
                    a0 = __builtin_amdgcn_mfma_f32_16x16x32_bf16(af, b0, a0, 0,0,0);
                    a1 = __builtin_amdgcn_mfma_f32_16x16x32_bf16(af, b1, a1, 0,0,0);
                }
                #pragma unroll
                for (int q = 0; q < 4; ++q){
                    float s0 = a0[q] + beta0;
                    float s1 = a1[q] + beta1;
                    float t0 = __shfl_xor(s0, 8, 64);
                    float t1 = __shfl_xor(s1, 8, 64);
                    float gi = bit3 ? t0 : s0;
                    float gf = bit3 ? s0 : t0;
                    float gg = bit3 ? t1 : s1;
                    float go = bit3 ? s1 : t1;
                    float cn = sigf(gf)*c2[q] + sigf(gi)*tanhf_(gg);
                    c2[q] = cn;
                    if (!bit3){
                        int row = row_base + lhi*4 + q;
                        h2next[row*Hz + j] = (__bf16)(sigf(go)*tanhf_(cn));
                    }
                }
            }
            __builtin_amdgcn_fence(__ATOMIC_RELEASE, "agent");
            grid.sync();
            __builtin_amdgcn_fence(__ATOMIC_ACQUIRE, "agent");
        }
    }
}

// ---- final logits + softmax: one 64-lane block per batch row ----
__global__ void logits_softmax(const __bf16* __restrict__ h2, const float* __restrict__ fcw,
                               const float* __restrict__ fcb, float* __restrict__ out)
{
    int row = blockIdx.x;
    int lane = threadIdx.x;
    float acc[11];
    #pragma unroll
    for (int o = 0; o < 11; ++o) acc[o] = 0.f;
    for (int it = 0; it < 8; ++it){
        int jj = it*64 + lane;
        float hv = (float)h2[row*512 + jj];
        #pragma unroll
        for (int o = 0; o < 11; ++o) acc[o] += hv * fcw[jj*11 + o];
    }
    #pragma unroll
    for (int o = 0; o < 11; ++o)
        for (int s = 32; s >= 1; s >>= 1) acc[o] += __shfl_xor(acc[o], s, 64);
    float m = -1e30f;
    #pragma unroll
    for (int o = 0; o < 11; ++o){ acc[o] += fcb[o]; m = fmaxf(m, acc[o]); }
    float ssum = 0.f;
    #pragma unroll
    for (int o = 0; o < 11; ++o){ acc[o] = __expf(acc[o] - m); ssum += acc[o]; }
    float inv = 1.0f/ssum;
    if (lane < 11) out[row*11 + lane] = acc[lane]*inv;
}

extern "C" void kernel_launch(void* const* d_in, const int* in_sizes, int n_in,
                              void* d_out, int out_size, void* d_ws, size_t ws_size,
                              hipStream_t stream)
{
    const float* x    = (const float*)d_in[0];
    const float* wih1 = (const float*)d_in[1];
    const float* whh1 = (const float*)d_in[2];
    const float* bih1 = (const float*)d_in[3];
    const float* bhh1 = (const float*)d_in[4];
    const float* wih2 = (const float*)d_in[5];
    const float* whh2 = (const float*)d_in[6];
    const float* bih2 = (const float*)d_in[7];
    const float* bhh2 = (const float*)d_in[8];
    const float* fcw  = (const float*)d_in[9];
    const float* fcb  = (const float*)d_in[10];
    float* out = (float*)d_out;

    char* p = (char*)d_ws;
    __bf16* w1p = (__bf16*)p;  p += (size_t)512*2048*2;   // 2 MB
    __bf16* w2p = (__bf16*)p;  p += (size_t)1024*2048*2;  // 4 MB
    float*  b1s = (float*)p;   p += 2048*4;
    float*  b2s = (float*)p;   p += 2048*4;
    __bf16* h1b = (__bf16*)p;  p += (size_t)2*BHz*2;      // 512 KB
    __bf16* h2b = (__bf16*)p;  p += (size_t)2*BHz*2;      // 512 KB

    hipMemsetAsync(h1b, 0, (size_t)2*BHz*2, stream);
    hipMemsetAsync(h2b, 0, (size_t)2*BHz*2, stream);
    pack_w1 <<<4096, 256, 0, stream>>>(whh1, w1p);
    pack_w2 <<<8192, 256, 0, stream>>>(wih2, whh2, w2p);
    pack_bias<<<8,   256, 0, stream>>>(bih1, bhh1, bih2, bhh2, b1s, b2s);

    void* args[8];
    args[0] = (void*)&x;   args[1] = (void*)&wih1;
    args[2] = (void*)&b1s; args[3] = (void*)&b2s;
    args[4] = (void*)&w1p; args[5] = (void*)&w2p;
    args[6] = (void*)&h1b; args[7] = (void*)&h2b;
    hipLaunchCooperativeKernel((void*)lstm_persistent, dim3(384), dim3(256), args, 0, stream);

    logits_softmax<<<256, 64, 0, stream>>>(h2b + BHz, fcw, fcb, out);
}

// Round 2
// 13909.924 us; speedup vs baseline: 3.5038x; 3.5038x over previous
//
#include <hip/hip_runtime.h>
#include <hip/hip_bf16.h>

#define Bz  256
#define Tz  512
#define Hz  512
#define BHz (Bz*Hz)   // elements in one h buffer
#define NBLK 384

typedef __bf16 bf16x8 __attribute__((ext_vector_type(8)));
typedef float  f32x4  __attribute__((ext_vector_type(4)));

__device__ __forceinline__ float sigf(float x)   { return 1.0f/(1.0f+__expf(-x)); }
__device__ __forceinline__ float tanhf_(float x) { return 2.0f/(1.0f+__expf(-2.0f*x)) - 1.0f; }

// ---- custom grid barrier: sense-free monotone epoch ----
// cnt/epoch in device memory (zeroed each call). One arrival atomic per block;
// spin on relaxed agent-scope load + s_sleep. Release fence before arrival
// publishes h stores (L2 writeback); acquire fence after ensures fresh reads.
__device__ __forceinline__ void gbar_sync(unsigned* cnt, unsigned* epoch, unsigned target){
    __syncthreads();
    if (threadIdx.x == 0){
        __builtin_amdgcn_fence(__ATOMIC_RELEASE, "agent");
        unsigned old = __hip_atomic_fetch_add(cnt, 1u, __ATOMIC_RELAXED, __HIP_MEMORY_SCOPE_AGENT);
        if (old == NBLK - 1){
            __hip_atomic_store(cnt, 0u, __ATOMIC_RELAXED, __HIP_MEMORY_SCOPE_AGENT);
            __hip_atomic_fetch_add(epoch, 1u, __ATOMIC_RELEASE, __HIP_MEMORY_SCOPE_AGENT);
        } else {
            while (__hip_atomic_load(epoch, __ATOMIC_RELAXED, __HIP_MEMORY_SCOPE_AGENT) < target)
                __builtin_amdgcn_s_sleep(1);
        }
        __builtin_amdgcn_fence(__ATOMIC_ACQUIRE, "agent");
    }
    __syncthreads();
}

// ---- pack w_hh1 [512][2048] f32 -> bf16 MFMA B-fragment layout ----
__global__ void pack_w1(const float* __restrict__ w, __bf16* __restrict__ out){
    int idx = blockIdx.x*256 + threadIdx.x;           // 1,048,576 total
    int i = idx & 7, lane = (idx>>3)&63, kb = (idx>>9)&15, nt = idx>>13;
    int k   = kb*32 + (lane>>4)*8 + i;
    int col = nt*16 + (lane&15);
    out[idx] = (__bf16)w[k*2048 + col];
}

// ---- pack [w_ih2; w_hh2] (K=1024) with layer-2 gate-interleaved column order ----
__global__ void pack_w2(const float* __restrict__ wih, const float* __restrict__ whh,
                        __bf16* __restrict__ out){
    int idx = blockIdx.x*256 + threadIdx.x;           // 2,097,152 total
    int i = idx & 7, lane = (idx>>3)&63, f = (idx>>9)&1, kb = (idx>>10)&31, nt = idx>>15;
    int k  = kb*32 + (lane>>4)*8 + i;
    int cc = f*16 + (lane&15);
    int col = (cc>>3)*512 + nt*8 + (cc&7);
    float v = (k < 512) ? wih[k*2048 + col] : whh[(k-512)*2048 + col];
    out[idx] = (__bf16)v;
}

__global__ void pack_bias(const float* a, const float* b, const float* c, const float* d,
                          float* b1s, float* b2s){
    int i = blockIdx.x*256 + threadIdx.x;
    if (i < 2048){ b1s[i] = a[i]+b[i]; b2s[i] = c[i]+d[i]; }
}

// ---- persistent pipelined 2-layer LSTM ----
// blocks 0..127  : layer1 tile (64 rows x 16 hcols x 4 gates), step p
// blocks 128..383: layer2 tile (64 rows x  8 hcols x 4 gates), step p-1
// one custom barrier per phase; c1/c2 live in registers for all 512 steps.
__launch_bounds__(256, 2)
__global__ void lstm_persistent(const float* __restrict__ x,      // [B][T][2]
                                const float* __restrict__ wih1,   // [2][2048]
                                const float* __restrict__ b1s,    // [2048]
                                const float* __restrict__ b2s,    // [2048]
                                const __bf16* __restrict__ w1p,
                                const __bf16* __restrict__ w2p,
                                __bf16* __restrict__ h1b,         // 2 x [B][H]
                                __bf16* __restrict__ h2b,         // 2 x [B][H]
                                unsigned* __restrict__ bar)       // [0]=cnt, [32]=epoch
{
    unsigned* cnt   = bar;
    unsigned* epoch = bar + 32;
    const int w    = blockIdx.x;
    const int tid  = threadIdx.x;
    const int v    = tid >> 6;
    const int lane = tid & 63;
    const int lhi  = lane >> 4, llo = lane & 15;

    if (w < 128){
        // ---------------- layer 1 ----------------
        const int mt = w >> 5, ntw = w & 31;
        const int row_base = mt*64 + v*16;
        const int j = ntw*16 + llo;                 // hidden col for C/D lane mapping
        float wa[4], wb[4], bb[4];
        #pragma unroll
        for (int g = 0; g < 4; ++g){
            int col = g*512 + j;
            wa[g] = wih1[col]; wb[g] = wih1[2048 + col]; bb[g] = b1s[col];
        }
        const __bf16* bp[4];
        #pragma unroll
        for (int g = 0; g < 4; ++g) bp[g] = w1p + (size_t)(g*32 + ntw)*8192 + lane*8;
        const int aoff = (row_base + llo)*Hz + lhi*8;
        const float2* x2 = reinterpret_cast<const float2*>(x);
        float c1[4] = {0.f,0.f,0.f,0.f};

        for (int p = 0; p <= Tz; ++p){
            if (p < Tz){
                const __bf16* h1prev = h1b + ((p+1)&1)*BHz;
                __bf16*       h1next = h1b + (p&1)*BHz;
                f32x4 a0={0,0,0,0}, a1={0,0,0,0}, a2={0,0,0,0}, a3={0,0,0,0};
                #pragma unroll 2
                for (int kb = 0; kb < 16; ++kb){
                    bf16x8 af = *reinterpret_cast<const bf16x8*>(h1prev + aoff + kb*32);
                    bf16x8 b0 = *reinterpret_cast<const bf16x8*>(bp[0] + kb*512);
                    bf16x8 b1 = *reinterpret_cast<const bf16x8*>(bp[1] + kb*512);
                    bf16x8 b2 = *reinterpret_cast<const bf16x8*>(bp[2] + kb*512);
                    bf16x8 b3 = *reinterpret_cast<const bf16x8*>(bp[3] + kb*512);
                    a0 = __builtin_amdgcn_mfma_f32_16x16x32_bf16(af, b0, a0, 0,0,0);
                    a1 = __builtin_amdgcn_mfma_f32_16x16x32_bf16(af, b1, a1, 0,0,0);
                    a2 = __builtin_amdgcn_mfma_f32_16x16x32_bf16(af, b2, a2, 0,0,0);
                    a3 = __builtin_amdgcn_mfma_f32_16x16x32_bf16(af, b3, a3, 0,0,0);
                }
                #pragma unroll
                for (int q = 0; q < 4; ++q){
                    int row = row_base + lhi*4 + q;
                    float2 xv = x2[row*Tz + p];
                    float gi = a0[q] + xv.x*wa[0] + xv.y*wb[0] + bb[0];
                    float gf = a1[q] + xv.x*wa[1] + xv.y*wb[1] + bb[1];
                    float gg = a2[q] + xv.x*wa[2] + xv.y*wb[2] + bb[2];
                    float go = a3[q] + xv.x*wa[3] + xv.y*wb[3] + bb[3];
                    float cn = sigf(gf)*c1[q] + sigf(gi)*tanhf_(gg);
                    c1[q] = cn;
                    h1next[row*Hz + j] = (__bf16)(sigf(go)*tanhf_(cn));
                }
            }
            gbar_sync(cnt, epoch, (unsigned)(p+1));
        }
    } else {
        // ---------------- layer 2 ----------------
        const int u = w - 128;
        const int nt2 = u >> 2, mt = u & 3;
        const int row_base = mt*64 + v*16;
        const int j = nt2*8 + (lane & 7);
        const int bit3 = (lane >> 3) & 1;
        const float beta0 = b2s[bit3*512 + j];        // i (bit3=0) or f (bit3=1)
        const float beta1 = b2s[(2 + bit3)*512 + j];  // g or o
        const int aoff = (row_base + llo)*Hz + lhi*8;
        const __bf16* b2base = w2p + (size_t)nt2*32768 + lane*8;
        float c2[4] = {0.f,0.f,0.f,0.f};

        for (int p = 0; p <= Tz; ++p){
            if (p >= 1){
                const __bf16* h1cur  = h1b + ((p+1)&1)*BHz;   // h1[p-1]
                const __bf16* h2prev = h2b + (p&1)*BHz;       // h2[p-2]
                __bf16*       h2next = h2b + ((p+1)&1)*BHz;   // h2[p-1]
                f32x4 a0={0,0,0,0}, a1={0,0,0,0};
                #pragma unroll 2
                for (int kb = 0; kb < 16; ++kb){
                    bf16x8 af = *reinterpret_cast<const bf16x8*>(h1cur + aoff + kb*32);
                    bf16x8 b0 = *reinterpret_cast<const bf16x8*>(b2base + kb*1024);
                    bf16x8 b1 = *reinterpret_cast<const bf16x8*>(b2base + kb*1024 + 512);
                    a0 = __builtin_amdgcn_mfma_f32_16x16x32_bf16(af, b0, a0, 0,0,0);
                    a1 = __builtin_amdgcn_mfma_f32_16x16x32_bf16(af, b1, a1, 0,0,0);
                }
                #pragma unroll 2
                for (int kb = 16; kb < 32; ++kb){
                    bf16x8 af = *reinterpret_cast<const bf16x8*>(h2prev + aoff + (kb-16)*32);
                    bf16x8 b0 = *reinterpret_cast<const bf16x8*>(b2base + kb*1024);
                    bf16x8 b1 = *reinterpret_cast<const bf16x8*>(b2base + kb*1024 + 512);
                    a0 = __builtin_amdgcn_mfma_f32_16x16x32_bf16(af, b0, a0, 0,0,0);
                    a1 = __builtin_amdgcn_mfma_f32_16x16x32_bf16(af, b1, a1, 0,0,0);
                }
                #pragma unroll
                for (int q = 0; q < 4; ++q){
                    float s0 = a0[q] + beta0;
                    float s1 = a1[q] + beta1;
                    float t0 = __shfl_xor(s0, 8, 64);
                    float t1 = __shfl_xor(s1, 8, 64);
                    float gi = bit3 ? t0 : s0;
                    float gf = bit3 ? s0 : t0;
                    float gg = bit3 ? t1 : s1;
                    float go = bit3 ? s1 : t1;
                    float cn = sigf(gf)*c2[q] + sigf(gi)*tanhf_(gg);
                    c2[q] = cn;
                    if (!bit3){
                        int row = row_base + lhi*4 + q;
                        h2next[row*Hz + j] = (__bf16)(sigf(go)*tanhf_(cn));
                    }
                }
            }
            gbar_sync(cnt, epoch, (unsigned)(p+1));
        }
    }
}

// ---- final logits + softmax: one 64-lane block per batch row ----
__global__ void logits_softmax(const __bf16* __restrict__ h2, const float* __restrict__ fcw,
                               const float* __restrict__ fcb, float* __restrict__ out)
{
    int row = blockIdx.x;
    int lane = threadIdx.x;
    float acc[11];
    #pragma unroll
    for (int o = 0; o < 11; ++o) acc[o] = 0.f;
    for (int it = 0; it < 8; ++it){
        int jj = it*64 + lane;
        float hv = (float)h2[row*512 + jj];
        #pragma unroll
        for (int o = 0; o < 11; ++o) acc[o] += hv * fcw[jj*11 + o];
    }
    #pragma unroll
    for (int o = 0; o < 11; ++o)
        for (int s = 32; s >= 1; s >>= 1) acc[o] += __shfl_xor(acc[o], s, 64);
    float m = -1e30f;
    #pragma unroll
    for (int o = 0; o < 11; ++o){ acc[o] += fcb[o]; m = fmaxf(m, acc[o]); }
    float ssum = 0.f;
    #pragma unroll
    for (int o = 0; o < 11; ++o){ acc[o] = __expf(acc[o] - m); ssum += acc[o]; }
    float inv = 1.0f/ssum;
    if (lane < 11) out[row*11 + lane] = acc[lane]*inv;
}

extern "C" void kernel_launch(void* const* d_in, const int* in_sizes, int n_in,
                              void* d_out, int out_size, void* d_ws, size_t ws_size,
                              hipStream_t stream)
{
    const float* x    = (const float*)d_in[0];
    const float* wih1 = (const float*)d_in[1];
    const float* whh1 = (const float*)d_in[2];
    const float* bih1 = (const float*)d_in[3];
    const float* bhh1 = (const float*)d_in[4];
    const float* wih2 = (const float*)d_in[5];
    const float* whh2 = (const float*)d_in[6];
    const float* bih2 = (const float*)d_in[7];
    const float* bhh2 = (const float*)d_in[8];
    const float* fcw  = (const float*)d_in[9];
    const float* fcb  = (const float*)d_in[10];
    float* out = (float*)d_out;

    char* p = (char*)d_ws;
    __bf16* w1p = (__bf16*)p;  p += (size_t)512*2048*2;   // 2 MB
    __bf16* w2p = (__bf16*)p;  p += (size_t)1024*2048*2;  // 4 MB
    float*  b1s = (float*)p;   p += 2048*4;
    float*  b2s = (float*)p;   p += 2048*4;
    __bf16* h1b = (__bf16*)p;  p += (size_t)2*BHz*2;      // 512 KB
    __bf16* h2b = (__bf16*)p;  p += (size_t)2*BHz*2;      // 512 KB
    unsigned* bar = (unsigned*)p; p += 256;               // [0]=cnt, [32]=epoch

    hipMemsetAsync(h1b, 0, (size_t)2*BHz*2, stream);
    hipMemsetAsync(h2b, 0, (size_t)2*BHz*2, stream);
    hipMemsetAsync(bar, 0, 256, stream);
    pack_w1 <<<4096, 256, 0, stream>>>(whh1, w1p);
    pack_w2 <<<8192, 256, 0, stream>>>(wih2, whh2, w2p);
    pack_bias<<<8,   256, 0, stream>>>(bih1, bhh1, bih2, bhh2, b1s, b2s);

    void* args[9];
    args[0] = (void*)&x;   args[1] = (void*)&wih1;
    args[2] = (void*)&b1s; args[3] = (void*)&b2s;
    args[4] = (void*)&w1p; args[5] = (void*)&w2p;
    args[6] = (void*)&h1b; args[7] = (void*)&h2b;
    args[8] = (void*)&bar;
    hipLaunchCooperativeKernel((void*)lstm_persistent, dim3(NBLK), dim3(256), args, 0, stream);

    logits_softmax<<<256, 64, 0, stream>>>(h2b + BHz, fcw, fcb, out);
}

// Round 4
// 7902.346 us; speedup vs baseline: 6.1674x; 1.7602x over previous
//
#include <hip/hip_runtime.h>
#include <hip/hip_bf16.h>

#define Tz  512
#define Hz  512
#define BHz (256*512)
#define NBLK 192

typedef __bf16 bf16x8 __attribute__((ext_vector_type(8)));
typedef float  f32x4  __attribute__((ext_vector_type(4)));

#define MFMA16(A,B,C) __builtin_amdgcn_mfma_f32_16x16x32_bf16(A,B,C,0,0,0)

__device__ __forceinline__ float sigf(float x){ return 1.0f/(1.0f+__expf(-x)); }
__device__ __forceinline__ float tanhf_(float x){ return 2.0f/(1.0f+__expf(-2.0f*x)) - 1.0f; }

// ---- pack w_hh1 [512][2048] f32 -> bf16 MFMA B-fragment layout (ROUND-2 verified) ----
__global__ void pack_w1(const float* __restrict__ w, __bf16* __restrict__ out){
    int idx = blockIdx.x*256 + threadIdx.x;           // 1,048,576 total
    int i = idx & 7, lane = (idx>>3)&63, kb = (idx>>9)&15, nt = idx>>13;
    int k   = kb*32 + (lane>>4)*8 + i;
    int col = nt*16 + (lane&15);
    out[idx] = (__bf16)w[k*2048 + col];
}

// ---- pack [w_ih2; w_hh2] (K=1024), gate-interleaved (ROUND-2 verified) ----
__global__ void pack_w2(const float* __restrict__ wih, const float* __restrict__ whh,
                        __bf16* __restrict__ out){
    int idx = blockIdx.x*256 + threadIdx.x;           // 2,097,152 total
    int i = idx & 7, lane = (idx>>3)&63, f = (idx>>9)&1, kb = (idx>>10)&31, nt = idx>>15;
    int k  = kb*32 + (lane>>4)*8 + i;
    int cc = f*16 + (lane&15);
    int col = (cc>>3)*512 + nt*8 + (cc&7);
    float v = (k < 512) ? wih[k*2048 + col] : whh[(k-512)*2048 + col];
    out[idx] = (__bf16)v;
}

__global__ void pack_bias(const float* a, const float* b, const float* c, const float* d,
                          float* b1s, float* b2s){
    int i = blockIdx.x*256 + threadIdx.x;
    if (i < 2048){ b1s[i] = a[i]+b[i]; b2s[i] = c[i]+d[i]; }
}

// ---- per-band 2-level tree barrier: 48 blocks = 8 subs x 6; monotone counters ----
__device__ __forceinline__ void group_barrier(unsigned* base, int sub, unsigned target){
    __syncthreads();
    if (threadIdx.x == 0){
        __builtin_amdgcn_fence(__ATOMIC_RELEASE, "agent");
        unsigned old = __hip_atomic_fetch_add(base + sub*64, 1u, __ATOMIC_RELAXED, __HIP_MEMORY_SCOPE_AGENT);
        if (old == target*6u - 1u){
            unsigned o2 = __hip_atomic_fetch_add(base + 8*64, 1u, __ATOMIC_RELAXED, __HIP_MEMORY_SCOPE_AGENT);
            if (o2 == target*8u - 1u)
                __hip_atomic_store(base + 9*64, target, __ATOMIC_RELEASE, __HIP_MEMORY_SCOPE_AGENT);
        }
        while (__hip_atomic_load(base + 9*64, __ATOMIC_RELAXED, __HIP_MEMORY_SCOPE_AGENT) < target)
            __builtin_amdgcn_s_sleep(1);
        __builtin_amdgcn_fence(__ATOMIC_ACQUIRE, "agent");
    }
    __syncthreads();
}

// ---- persistent 2-layer LSTM; 192 blocks x 256 thr; weights in VGPRs ----
// bid: band g = bid&3 (rows g*64..+63); t = bid>>2: t<16 -> layer1, else layer2.
// wave: rt = v&1 (32-row half); layer1 ct = t*2+(v>>1) (16 cols); layer2 nt2 = (t-16)*2+(v>>1) (8 cols).
__launch_bounds__(256, 1)
__global__ void lstm_persistent(const float* __restrict__ x,      // [B][T][2]
                                const float* __restrict__ wih1,   // [2][2048]
                                const float* __restrict__ b1s,
                                const float* __restrict__ b2s,
                                const __bf16* __restrict__ w1p,
                                const __bf16* __restrict__ w2p,
                                __bf16* __restrict__ h1b,         // 2 x [B][H]
                                __bf16* __restrict__ h2b,         // 2 x [B][H]
                                unsigned* __restrict__ bar)       // [4][16][64]
{
    const int bid = blockIdx.x;
    const int g   = bid & 3;
    const int t   = bid >> 2;          // 0..47
    const int sub = t & 7;
    unsigned* gbar = bar + g*1024;

    const int tid  = threadIdx.x;
    const int v    = tid >> 6;
    const int lane = tid & 63;
    const int lhi  = lane >> 4, llo = lane & 15;
    const int rt   = v & 1;
    const int rowb = g*64 + rt*32;
    const size_t ao0 = (size_t)(rowb + llo)*Hz + lhi*8;
    const size_t ao1 = ao0 + (size_t)16*Hz;

    if (t < 16){
        // ---------------- layer 1 ----------------
        const int ct = t*2 + (v>>1);              // 0..31
        const int j  = ct*16 + llo;
        float wa[4], wb[4], bb[4];
        #pragma unroll
        for (int g4 = 0; g4 < 4; ++g4){
            int col = g4*512 + j;
            wa[g4] = wih1[col]; wb[g4] = wih1[2048+col]; bb[g4] = b1s[col];
        }
        bf16x8 wf[64];                             // [gate(4)][kb(16)] B-frags
        #pragma unroll
        for (int q = 0; q < 64; ++q)
            wf[q] = *reinterpret_cast<const bf16x8*>(
                w1p + (size_t)((q>>4)*32 + ct)*8192 + (q&15)*512 + lane*8);
        const float2* x2 = reinterpret_cast<const float2*>(x);
        float c1a[4] = {0,0,0,0}, c1b[4] = {0,0,0,0};

        for (int p = 0; p <= Tz; ++p){
            if (p < Tz){
                const __bf16* h1prev = h1b + ((p+1)&1)*BHz;
                __bf16*       h1next = h1b + (p&1)*BHz;
                f32x4 A00={0,0,0,0},A01={0,0,0,0},A02={0,0,0,0},A03={0,0,0,0};
                f32x4 A10={0,0,0,0},A11={0,0,0,0},A12={0,0,0,0},A13={0,0,0,0};
                #pragma unroll
                for (int kb = 0; kb < 16; ++kb){
                    bf16x8 a0 = *reinterpret_cast<const bf16x8*>(h1prev + ao0 + kb*32);
                    bf16x8 a1 = *reinterpret_cast<const bf16x8*>(h1prev + ao1 + kb*32);
                    A00 = MFMA16(a0, wf[kb   ], A00);
                    A01 = MFMA16(a0, wf[16+kb], A01);
                    A02 = MFMA16(a0, wf[32+kb], A02);
                    A03 = MFMA16(a0, wf[48+kb], A03);
                    A10 = MFMA16(a1, wf[kb   ], A10);
                    A11 = MFMA16(a1, wf[16+kb], A11);
                    A12 = MFMA16(a1, wf[32+kb], A12);
                    A13 = MFMA16(a1, wf[48+kb], A13);
                }
                #pragma unroll
                for (int q = 0; q < 4; ++q){
                    int row = rowb + lhi*4 + q;
                    float2 xv = x2[(size_t)row*Tz + p];
                    float gi = A00[q] + xv.x*wa[0] + xv.y*wb[0] + bb[0];
                    float gf = A01[q] + xv.x*wa[1] + xv.y*wb[1] + bb[1];
                    float gg = A02[q] + xv.x*wa[2] + xv.y*wb[2] + bb[2];
                    float go = A03[q] + xv.x*wa[3] + xv.y*wb[3] + bb[3];
                    float cn = sigf(gf)*c1a[q] + sigf(gi)*tanhf_(gg);
                    c1a[q] = cn;
                    h1next[(size_t)row*Hz + j] = (__bf16)(sigf(go)*tanhf_(cn));
                }
                #pragma unroll
                for (int q = 0; q < 4; ++q){
                    int row = rowb + 16 + lhi*4 + q;
                    float2 xv = x2[(size_t)row*Tz + p];
                    float gi = A10[q] + xv.x*wa[0] + xv.y*wb[0] + bb[0];
                    float gf = A11[q] + xv.x*wa[1] + xv.y*wb[1] + bb[1];
                    float gg = A12[q] + xv.x*wa[2] + xv.y*wb[2] + bb[2];
                    float go = A13[q] + xv.x*wa[3] + xv.y*wb[3] + bb[3];
                    float cn = sigf(gf)*c1b[q] + sigf(gi)*tanhf_(gg);
                    c1b[q] = cn;
                    h1next[(size_t)row*Hz + j] = (__bf16)(sigf(go)*tanhf_(cn));
                }
            }
            group_barrier(gbar, sub, (unsigned)(p+1));
        }
    } else {
        // ---------------- layer 2 ----------------
        const int u    = t - 16;                   // 0..31
        const int nt2  = u*2 + (v>>1);             // 0..63
        const int j    = nt2*8 + (lane & 7);
        const int bit3 = (lane >> 3) & 1;
        const float beta0 = b2s[bit3*512 + j];        // i or f
        const float beta1 = b2s[(2 + bit3)*512 + j];  // g or o
        bf16x8 wf[64];                             // [kb(32)][chain(2)] B-frags
        #pragma unroll
        for (int q = 0; q < 64; ++q)
            wf[q] = *reinterpret_cast<const bf16x8*>(
                w2p + (size_t)nt2*32768 + (q>>1)*1024 + (q&1)*512 + lane*8);
        float c2a[4] = {0,0,0,0}, c2b[4] = {0,0,0,0};

        for (int p = 0; p <= Tz; ++p){
            if (p >= 1){
                const __bf16* h1cur  = h1b + ((p+1)&1)*BHz;   // h1[p-1]
                const __bf16* h2prev = h2b + (p&1)*BHz;       // h2[p-2]
                __bf16*       h2next = h2b + ((p+1)&1)*BHz;   // h2[p-1]
                f32x4 P00={0,0,0,0},P01={0,0,0,0},P10={0,0,0,0},P11={0,0,0,0};
                #pragma unroll
                for (int kb = 0; kb < 16; ++kb){
                    bf16x8 a0 = *reinterpret_cast<const bf16x8*>(h1cur + ao0 + kb*32);
                    bf16x8 a1 = *reinterpret_cast<const bf16x8*>(h1cur + ao1 + kb*32);
                    P00 = MFMA16(a0, wf[2*kb  ], P00);
                    P01 = MFMA16(a0, wf[2*kb+1], P01);
                    P10 = MFMA16(a1, wf[2*kb  ], P10);
                    P11 = MFMA16(a1, wf[2*kb+1], P11);
                }
                #pragma unroll
                for (int kb = 16; kb < 32; ++kb){
                    bf16x8 a0 = *reinterpret_cast<const bf16x8*>(h2prev + ao0 + (kb-16)*32);
                    bf16x8 a1 = *reinterpret_cast<const bf16x8*>(h2prev + ao1 + (kb-16)*32);
                    P00 = MFMA16(a0, wf[2*kb  ], P00);
                    P01 = MFMA16(a0, wf[2*kb+1], P01);
                    P10 = MFMA16(a1, wf[2*kb  ], P10);
                    P11 = MFMA16(a1, wf[2*kb+1], P11);
                }
                #pragma unroll
                for (int q = 0; q < 4; ++q){
                    float s0 = P00[q] + beta0;
                    float s1 = P01[q] + beta1;
                    float u0 = __shfl_xor(s0, 8, 64);
                    float u1 = __shfl_xor(s1, 8, 64);
                    float gi = bit3 ? u0 : s0;
                    float gf = bit3 ? s0 : u0;
                    float gg = bit3 ? u1 : s1;
                    float go = bit3 ? s1 : u1;
                    float cn = sigf(gf)*c2a[q] + sigf(gi)*tanhf_(gg);
                    c2a[q] = cn;
                    if (!bit3)
                        h2next[(size_t)(rowb + lhi*4 + q)*Hz + j] = (__bf16)(sigf(go)*tanhf_(cn));
                }
                #pragma unroll
                for (int q = 0; q < 4; ++q){
                    float s0 = P10[q] + beta0;
                    float s1 = P11[q] + beta1;
                    float u0 = __shfl_xor(s0, 8, 64);
                    float u1 = __shfl_xor(s1, 8, 64);
                    float gi = bit3 ? u0 : s0;
                    float gf = bit3 ? s0 : u0;
                    float gg = bit3 ? u1 : s1;
                    float go = bit3 ? s1 : u1;
                    float cn = sigf(gf)*c2b[q] + sigf(gi)*tanhf_(gg);
                    c2b[q] = cn;
                    if (!bit3)
                        h2next[(size_t)(rowb + 16 + lhi*4 + q)*Hz + j] = (__bf16)(sigf(go)*tanhf_(cn));
                }
            }
            group_barrier(gbar, sub, (unsigned)(p+1));
        }
    }
}

// ---- final logits + softmax ----
__global__ void logits_softmax(const __bf16* __restrict__ h2, const float* __restrict__ fcw,
                               const float* __restrict__ fcb, float* __restrict__ out)
{
    int row = blockIdx.x;
    int lane = threadIdx.x;
    float acc[11];
    #pragma unroll
    for (int o = 0; o < 11; ++o) acc[o] = 0.f;
    for (int it = 0; it < 8; ++it){
        int jj = it*64 + lane;
        float hv = (float)h2[row*512 + jj];
        #pragma unroll
        for (int o = 0; o < 11; ++o) acc[o] += hv * fcw[jj*11 + o];
    }
    #pragma unroll
    for (int o = 0; o < 11; ++o)
        for (int s = 32; s >= 1; s >>= 1) acc[o] += __shfl_xor(acc[o], s, 64);
    float m = -1e30f;
    #pragma unroll
    for (int o = 0; o < 11; ++o){ acc[o] += fcb[o]; m = fmaxf(m, acc[o]); }
    float ssum = 0.f;
    #pragma unroll
    for (int o = 0; o < 11; ++o){ acc[o] = __expf(acc[o] - m); ssum += acc[o]; }
    float inv = 1.0f/ssum;
    if (lane < 11) out[row*11 + lane] = acc[lane]*inv;
}

extern "C" void kernel_launch(void* const* d_in, const int* in_sizes, int n_in,
                              void* d_out, int out_size, void* d_ws, size_t ws_size,
                              hipStream_t stream)
{
    const float* x    = (const float*)d_in[0];
    const float* wih1 = (const float*)d_in[1];
    const float* whh1 = (const float*)d_in[2];
    const float* bih1 = (const float*)d_in[3];
    const float* bhh1 = (const float*)d_in[4];
    const float* wih2 = (const float*)d_in[5];
    const float* whh2 = (const float*)d_in[6];
    const float* bih2 = (const float*)d_in[7];
    const float* bhh2 = (const float*)d_in[8];
    const float* fcw  = (const float*)d_in[9];
    const float* fcb  = (const float*)d_in[10];
    float* out = (float*)d_out;

    char* p = (char*)d_ws;
    __bf16* w1p = (__bf16*)p;  p += (size_t)512*2048*2;   // 2 MB
    __bf16* w2p = (__bf16*)p;  p += (size_t)1024*2048*2;  // 4 MB
    float*  b1s = (float*)p;   p += 2048*4;
    float*  b2s = (float*)p;   p += 2048*4;
    __bf16* h1b = (__bf16*)p;  p += (size_t)2*BHz*2;      // 512 KB
    __bf16* h2b = (__bf16*)p;  p += (size_t)2*BHz*2;      // 512 KB
    unsigned* bar = (unsigned*)p; p += 4*1024*4;          // 16 KB

    hipMemsetAsync(h1b, 0, (size_t)2*BHz*2, stream);
    hipMemsetAsync(h2b, 0, (size_t)2*BHz*2, stream);
    hipMemsetAsync(bar, 0, 4*1024*4, stream);
    pack_w1 <<<4096, 256, 0, stream>>>(whh1, w1p);
    pack_w2 <<<8192, 256, 0, stream>>>(wih2, whh2, w2p);
    pack_bias<<<8,   256, 0, stream>>>(bih1, bhh1, bih2, bhh2, b1s, b2s);

    // 192 blocks @ 1 block/CU on 256 CUs: all blocks trivially co-resident,
    // plain launch (no cooperative-launch validation failure mode).
    lstm_persistent<<<NBLK, 256, 0, stream>>>(x, wih1, b1s, b2s, w1p, w2p, h1b, h2b, bar);

    logits_softmax<<<256, 64, 0, stream>>>(h2b + BHz, fcw, fcb, out);
}